// Round 8
// baseline (245.432 us; speedup 1.0000x reference)
//
#include <hip/hip_runtime.h>
#include <hip/hip_bf16.h>

#define N_PED 1024
#define H 128
#define G 8
#define NCELL 64
#define K_TOT 8192
#define HALF_NB 16.0f
#define INV_CELL 0.25f

#define KSPLIT 16
#define KC 512          // K per block
#define BM 32
#define BK 64
#define NSTAGE 8        // KC/BK
#define REP 16          // DIAGNOSTIC: repeat each kernel body 16x so our
                        // dispatches exceed the ~44us harness-fill cutoff and
                        // show up in rocprof top-5 with per-kernel counters.

typedef __attribute__((ext_vector_type(8))) short bf16x8;
typedef __attribute__((ext_vector_type(4))) float f32x4;

__device__ __forceinline__ unsigned map_f2u(float v) {
    unsigned u = __float_as_uint(v);
    return (u & 0x80000000u) ? ~u : (u | 0x80000000u);
}
__device__ __forceinline__ float unmap_u2f(unsigned u) {
    return __uint_as_float((u & 0x80000000u) ? (u ^ 0x80000000u) : ~u);
}
__device__ __forceinline__ ushort f2bf(float f) {   // round-to-nearest-even
    unsigned u = __float_as_uint(f);
    return (ushort)((u + 0x7FFFu + ((u >> 16) & 1u)) >> 16);
}
__device__ __forceinline__ void gl_lds16(const void* g, void* l) {
    __builtin_amdgcn_global_load_lds(
        (const __attribute__((address_space(1))) void*)g,
        (__attribute__((address_space(3))) void*)l, 16, 0, 0);
}

// blocks 0..1023: build pooled grid row (bf16 [8192]) for pedestrian i
// blocks 1024..1151: convert+transpose a 64-k slab of W into Wt bf16 [128][8192]
__global__ __launch_bounds__(512) void fused_pre(const float* __restrict__ hs,
                                                 const float* __restrict__ pos,
                                                 const float* __restrict__ W,
                                                 ushort* __restrict__ grid,
                                                 ushort* __restrict__ Wt) {
    __shared__ __align__(16) char smem[36872];
    const int tid = threadIdx.x;

    for (int rep = 0; rep < REP; ++rep) {
        __syncthreads();   // rep boundary
        if (blockIdx.x < N_PED) {
            unsigned* lgrid = (unsigned*)smem;            // 32768 B
            int*      list  = (int*)(smem + 32768);       // 4096 B
            int*      cnt   = (int*)(smem + 36864);       // 4 B
            const int i = blockIdx.x;

            const unsigned iu = 0x80000000u;              // map_f2u(0.0f)
            uint4 iv = {iu, iu, iu, iu};
            for (int k = tid; k < NCELL * H / 4; k += 512) ((uint4*)lgrid)[k] = iv;
            if (tid == 0) *cnt = 0;
            __syncthreads();

            const float2 pi = ((const float2*)pos)[i];
            for (int j = tid; j < N_PED; j += 512) {
                float2 pj = ((const float2*)pos)[j];
                float rx = pj.x - pi.x;
                float ry = pj.y - pi.y;
                if (j != i && fabsf(rx) <= HALF_NB && fabsf(ry) <= HALF_NB) {
                    int gx = min(G - 1, max(0, (int)floorf((rx + HALF_NB) * INV_CELL)));
                    int gy = min(G - 1, max(0, (int)floorf((ry + HALF_NB) * INV_CELL)));
                    int slot = atomicAdd(cnt, 1);
                    list[slot] = (j << 8) | (gy * G + gx);
                }
            }
            __syncthreads();

            // pooling: 16-way entry parallel, 4 dims/thread, 2-deep prefetch
            const int n    = *cnt;
            const int dim4 = (tid & 31) * 4;
            const int eg   = tid >> 5;                    // 0..15
            int e  = eg;
            int p0 = (e < n) ? list[e] : -1;
            int p1 = (e + 16 < n) ? list[e + 16] : -1;
            float4 v0 = {};
            if (p0 >= 0) v0 = *(const float4*)&hs[(p0 >> 8) * H + dim4];
            while (p0 >= 0) {
                int p2 = (e + 32 < n) ? list[e + 32] : -1;
                float4 v1 = {};
                if (p1 >= 0) v1 = *(const float4*)&hs[(p1 >> 8) * H + dim4];
                unsigned* gph = &lgrid[(p0 & 255) * H + dim4];
                atomicMax(gph + 0, map_f2u(v0.x));
                atomicMax(gph + 1, map_f2u(v0.y));
                atomicMax(gph + 2, map_f2u(v0.z));
                atomicMax(gph + 3, map_f2u(v0.w));
                e += 16; p0 = p1; p1 = p2; v0 = v1;
            }
            __syncthreads();

            ushort* dst = grid + (size_t)i * K_TOT;
            for (int c = tid; c < K_TOT / 8; c += 512) {
                uint4 a = ((const uint4*)lgrid)[2 * c];
                uint4 bq = ((const uint4*)lgrid)[2 * c + 1];
                ushort tmp[8];
                tmp[0] = f2bf(unmap_u2f(a.x));  tmp[1] = f2bf(unmap_u2f(a.y));
                tmp[2] = f2bf(unmap_u2f(a.z));  tmp[3] = f2bf(unmap_u2f(a.w));
                tmp[4] = f2bf(unmap_u2f(bq.x)); tmp[5] = f2bf(unmap_u2f(bq.y));
                tmp[6] = f2bf(unmap_u2f(bq.z)); tmp[7] = f2bf(unmap_u2f(bq.w));
                *(bf16x8*)&dst[8 * c] = *(const bf16x8*)tmp;
            }
        } else {
            float* tile = (float*)smem;                   // [64][129] = 33024 B
            const int bw  = blockIdx.x - N_PED;
            const int k0w = bw * 64;

            for (int x = tid; x < 64 * H; x += 512) {
                int r = x >> 7, c = x & 127;
                tile[r * 129 + c] = W[(size_t)(k0w + r) * H + c];
            }
            __syncthreads();

            const int col = tid >> 2;                     // 0..127
            const int kh  = (tid & 3) * 16;
            ushort tmp[16];
            #pragma unroll
            for (int t = 0; t < 16; ++t) tmp[t] = f2bf(tile[(kh + t) * 129 + col]);
            ushort* w0 = Wt + (size_t)col * K_TOT + k0w + kh;
            *(bf16x8*)w0       = *(const bf16x8*)&tmp[0];
            *(bf16x8*)(w0 + 8) = *(const bf16x8*)&tmp[8];
        }
    }
}

// A[1024][8192] bf16 @ Wt[128][8192] bf16 -> partial fp32 [KSPLIT][1024][128]
// Triple-buffered LDS, counted vmcnt(5), raw s_barrier.
__global__ __launch_bounds__(256) void gemm_mfma(const ushort* __restrict__ A,
                                                 const ushort* __restrict__ Wt,
                                                 float* __restrict__ part) {
    __shared__ ushort sA[3][BM * BK];   // 3 x 4 KB
    __shared__ ushort sB[3][H * BK];    // 3 x 16 KB

    const int m0   = blockIdx.x * BM;
    const int k0   = blockIdx.y * KC;
    const int tid  = threadIdx.x;
    const int wave = tid >> 6;
    const int lane = tid & 63;
    const int ll   = lane & 15;
    const int lh   = lane >> 4;
    const int lr8  = lane >> 3;                 // 0..7 row-in-group
    const int cswz = (lane & 7) ^ (lr8 & 7);    // swizzled chunk to fetch

    const ushort* Abase = A  + (size_t)(m0 + 8 * wave + lr8) * K_TOT + k0 + cswz * 8;
    const ushort* Bbase = Wt + (size_t)(32 * wave + lr8) * K_TOT      + k0 + cswz * 8;

#define STAGE(T, BUF)                                                        \
    do {                                                                     \
        gl_lds16(Abase + (T) * BK, &sA[BUF][8 * wave * BK]);                 \
        gl_lds16(Bbase + (T) * BK,                &sB[BUF][(32 * wave) * BK]);      \
        gl_lds16(Bbase + (T) * BK +  8 * K_TOT,   &sB[BUF][(32 * wave + 8) * BK]);  \
        gl_lds16(Bbase + (T) * BK + 16 * K_TOT,   &sB[BUF][(32 * wave + 16) * BK]); \
        gl_lds16(Bbase + (T) * BK + 24 * K_TOT,   &sB[BUF][(32 * wave + 24) * BK]); \
    } while (0)

    for (int rep = 0; rep < REP; ++rep) {
        f32x4 acc[2][2] = {};   // [mt][nt]

        // prologue: stages 0,1 in flight; drain 0 (stores from prior rep also
        // drain under vmcnt(5) -- over-sync, still correct); barrier
        STAGE(0, 0);
        STAGE(1, 1);
        asm volatile("s_waitcnt vmcnt(5)" ::: "memory");
        __builtin_amdgcn_s_barrier();

        #pragma unroll
        for (int t = 0; t < NSTAGE; ++t) {
            if (t + 2 < NSTAGE) STAGE(t + 2, (t + 2) % 3);

            const int buf = t % 3;
            #pragma unroll
            for (int ks = 0; ks < 2; ++ks) {
                const int chunk = ks * 4 + lh;      // 16B chunk index
                bf16x8 bfrag[2], afrag[2];
                #pragma unroll
                for (int nt = 0; nt < 2; ++nt) {
                    int br = wave * 32 + nt * 16 + ll;
                    bfrag[nt] = *(const bf16x8*)&sB[buf][br * BK + ((chunk ^ (br & 7)) * 8)];
                }
                #pragma unroll
                for (int mt = 0; mt < 2; ++mt) {
                    int ar = mt * 16 + ll;
                    afrag[mt] = *(const bf16x8*)&sA[buf][ar * BK + ((chunk ^ (ar & 7)) * 8)];
                }
                #pragma unroll
                for (int mt = 0; mt < 2; ++mt)
                    #pragma unroll
                    for (int nt = 0; nt < 2; ++nt)
                        acc[mt][nt] = __builtin_amdgcn_mfma_f32_16x16x32_bf16(
                            afrag[mt], bfrag[nt], acc[mt][nt], 0, 0, 0);
            }

            if (t + 1 < NSTAGE) {
                if (t + 2 < NSTAGE)
                    asm volatile("s_waitcnt vmcnt(5)" ::: "memory");
                else
                    asm volatile("s_waitcnt vmcnt(0)" ::: "memory");
                __builtin_amdgcn_s_barrier();
            }
        }

        // D layout: col = lane&15, row = (lane>>4)*4 + reg   [m89/m91]
        float* dst = part + (size_t)blockIdx.y * (N_PED * H);
        #pragma unroll
        for (int mt = 0; mt < 2; ++mt)
            #pragma unroll
            for (int nt = 0; nt < 2; ++nt) {
                int col   = wave * 32 + nt * 16 + ll;
                int rbase = m0 + mt * 16 + lh * 4;
                #pragma unroll
                for (int r = 0; r < 4; ++r)
                    dst[(size_t)(rbase + r) * H + col] = acc[mt][nt][r];
            }
        __builtin_amdgcn_s_barrier();   // rep boundary (WAR on sA/sB buf 0/1)
    }
#undef STAGE
}

// out = bias + sum over KSPLIT partials
__global__ __launch_bounds__(128) void reduce_out(const float* __restrict__ part,
                                                  const float* __restrict__ b,
                                                  float* __restrict__ out) {
    const int idx = (blockIdx.x * 128 + threadIdx.x) * 4;   // 256 blocks
    for (int rep = 0; rep < REP; ++rep) {
        float4 acc = *(const float4*)&b[idx & (H - 1)];
        #pragma unroll
        for (int s = 0; s < KSPLIT; ++s) {
            float4 p = *(const float4*)&part[(size_t)s * (N_PED * H) + idx];
            acc.x += p.x; acc.y += p.y; acc.z += p.z; acc.w += p.w;
        }
        *(float4*)&out[idx] = acc;
    }
}

extern "C" void kernel_launch(void* const* d_in, const int* in_sizes, int n_in,
                              void* d_out, int out_size, void* d_ws, size_t ws_size,
                              hipStream_t stream) {
    const float* hs  = (const float*)d_in[0];   // [1024][128]
    const float* pos = (const float*)d_in[1];   // [1024][2]
    const float* Wm  = (const float*)d_in[2];   // [8192][128]
    const float* b   = (const float*)d_in[3];   // [128]
    float* out = (float*)d_out;                 // [1024][128]

    ushort* grid = (ushort*)d_ws;                               // 16 MB
    ushort* Wt   = (ushort*)((char*)d_ws + (16u << 20));        // 2 MB
    float*  part = (float*)((char*)d_ws + (18u << 20));         // 8 MB

    fused_pre<<<N_PED + K_TOT / 64, 512, 0, stream>>>(hs, pos, Wm, grid, Wt);
    gemm_mfma<<<dim3(N_PED / BM, KSPLIT), 256, 0, stream>>>(grid, Wt, part);
    reduce_out<<<(N_PED * H) / (128 * 4), 128, 0, stream>>>(part, b, out);
}

// Round 9
// 86.167 us; speedup vs baseline: 2.8483x; 2.8483x over previous
//
#include <hip/hip_runtime.h>
#include <hip/hip_bf16.h>

#define N_PED 1024
#define H 128
#define G 8
#define NCELL 64
#define K_TOT 8192
#define HALF_NB 16.0f
#define INV_CELL 0.25f

#define KSPLIT 16
#define KC 512          // K per gemm block
#define BM 32
#define BK 64
#define NSTAGE 8        // KC/BK

typedef __attribute__((ext_vector_type(8))) short bf16x8;
typedef __attribute__((ext_vector_type(4))) float f32x4;

__device__ __forceinline__ unsigned map_f2u(float v) {
    unsigned u = __float_as_uint(v);
    return (u & 0x80000000u) ? ~u : (u | 0x80000000u);
}
__device__ __forceinline__ float unmap_u2f(unsigned u) {
    return __uint_as_float((u & 0x80000000u) ? (u ^ 0x80000000u) : ~u);
}
__device__ __forceinline__ ushort f2bf(float f) {   // round-to-nearest-even
    unsigned u = __float_as_uint(f);
    return (ushort)((u + 0x7FFFu + ((u >> 16) & 1u)) >> 16);
}
__device__ __forceinline__ void gl_lds16(const void* g, void* l) {
    __builtin_amdgcn_global_load_lds(
        (const __attribute__((address_space(1))) void*)g,
        (__attribute__((address_space(3))) void*)l, 16, 0, 0);
}

// blocks 0..1023  : build pooled grid row (bf16 [8192]) for pedestrian i
// blocks 1024..1151: convert+transpose 64-k slab of W into Wt bf16 [128][8192]
//                    (block 1024 also zeroes the 32 split-K semaphores)
__global__ __launch_bounds__(512) void fused_pre(const float* __restrict__ hs,
                                                 const float* __restrict__ pos,
                                                 const float* __restrict__ W,
                                                 ushort* __restrict__ grid,
                                                 ushort* __restrict__ Wt,
                                                 int* __restrict__ sem) {
    __shared__ __align__(16) char smem[36872];
    const int tid = threadIdx.x;

    if (blockIdx.x < N_PED) {
        unsigned* lgrid = (unsigned*)smem;            // 32768 B
        int*      list  = (int*)(smem + 32768);       // 4096 B
        int*      cnt   = (int*)(smem + 36864);       // 4 B
        const int i = blockIdx.x;

        const unsigned iu = 0x80000000u;              // map_f2u(0.0f)
        uint4 iv = {iu, iu, iu, iu};
        for (int k = tid; k < NCELL * H / 4; k += 512) ((uint4*)lgrid)[k] = iv;
        if (tid == 0) *cnt = 0;
        __syncthreads();

        const float2 pi = ((const float2*)pos)[i];
        for (int j = tid; j < N_PED; j += 512) {
            float2 pj = ((const float2*)pos)[j];
            float rx = pj.x - pi.x;
            float ry = pj.y - pi.y;
            if (j != i && fabsf(rx) <= HALF_NB && fabsf(ry) <= HALF_NB) {
                int gx = min(G - 1, max(0, (int)floorf((rx + HALF_NB) * INV_CELL)));
                int gy = min(G - 1, max(0, (int)floorf((ry + HALF_NB) * INV_CELL)));
                int slot = atomicAdd(cnt, 1);
                list[slot] = (j << 8) | (gy * G + gx);
            }
        }
        __syncthreads();

        // pooling: 16-way entry parallel; lane c owns dims {c,c+32,c+64,c+96}
        // -> atomic bank = c: conflict-free (2 half-waves/bank = free, m136)
        const int n  = *cnt;
        const int c  = tid & 31;
        const int eg = tid >> 5;                      // 0..15
        int e  = eg;
        int p0 = (e < n) ? list[e] : -1;
        int p1 = (e + 16 < n) ? list[e + 16] : -1;
        float v0[4] = {};
        if (p0 >= 0) {
            const float* hp = &hs[(p0 >> 8) * H + c];
            v0[0] = hp[0]; v0[1] = hp[32]; v0[2] = hp[64]; v0[3] = hp[96];
        }
        while (p0 >= 0) {
            int p2 = (e + 32 < n) ? list[e + 32] : -1;
            float v1[4] = {};
            if (p1 >= 0) {
                const float* hp = &hs[(p1 >> 8) * H + c];
                v1[0] = hp[0]; v1[1] = hp[32]; v1[2] = hp[64]; v1[3] = hp[96];
            }
            unsigned* gph = &lgrid[(p0 & 255) * H + c];
            atomicMax(gph + 0,  map_f2u(v0[0]));
            atomicMax(gph + 32, map_f2u(v0[1]));
            atomicMax(gph + 64, map_f2u(v0[2]));
            atomicMax(gph + 96, map_f2u(v0[3]));
            e += 16; p0 = p1; p1 = p2;
            v0[0] = v1[0]; v0[1] = v1[1]; v0[2] = v1[2]; v0[3] = v1[3];
        }
        __syncthreads();

        ushort* dst = grid + (size_t)i * K_TOT;
        for (int q = tid; q < K_TOT / 8; q += 512) {
            uint4 a  = ((const uint4*)lgrid)[2 * q];
            uint4 bq = ((const uint4*)lgrid)[2 * q + 1];
            ushort tmp[8];
            tmp[0] = f2bf(unmap_u2f(a.x));  tmp[1] = f2bf(unmap_u2f(a.y));
            tmp[2] = f2bf(unmap_u2f(a.z));  tmp[3] = f2bf(unmap_u2f(a.w));
            tmp[4] = f2bf(unmap_u2f(bq.x)); tmp[5] = f2bf(unmap_u2f(bq.y));
            tmp[6] = f2bf(unmap_u2f(bq.z)); tmp[7] = f2bf(unmap_u2f(bq.w));
            *(bf16x8*)&dst[8 * q] = *(const bf16x8*)tmp;
        }
    } else {
        float* tile = (float*)smem;                   // [64][129] = 33024 B
        const int bw  = blockIdx.x - N_PED;
        const int k0w = bw * 64;

        if (bw == 0 && tid < 32) sem[tid] = 0;        // zero split-K semaphores

        for (int x = tid; x < 64 * H; x += 512) {
            int r = x >> 7, cc = x & 127;
            tile[r * 129 + cc] = W[(size_t)(k0w + r) * H + cc];
        }
        __syncthreads();

        const int col = tid >> 2;                     // 0..127
        const int kh  = (tid & 3) * 16;
        ushort tmp[16];
        #pragma unroll
        for (int t = 0; t < 16; ++t) tmp[t] = f2bf(tile[(kh + t) * 129 + col]);
        ushort* w0 = Wt + (size_t)col * K_TOT + k0w + kh;
        *(bf16x8*)w0       = *(const bf16x8*)&tmp[0];
        *(bf16x8*)(w0 + 8) = *(const bf16x8*)&tmp[8];
    }
}

// A[1024][8192] bf16 @ Wt[128][8192] bf16 -> part [KSPLIT][1024][128] fp32;
// the 16th-arriving block per m-tile reduces all slices + bias into out
// (split-K semaphore: fence -> sync -> tid0 atomicAdd -> winner fences+reduces;
// fixed summation order => deterministic).
__global__ __launch_bounds__(256) void gemm_mfma(const ushort* __restrict__ A,
                                                 const ushort* __restrict__ Wt,
                                                 float* __restrict__ part,
                                                 const float* __restrict__ b,
                                                 float* __restrict__ out,
                                                 int* __restrict__ sem) {
    __shared__ ushort sA[3][BM * BK];   // 3 x 4 KB
    __shared__ ushort sB[3][H * BK];    // 3 x 16 KB
    __shared__ int    winner;

    const int m0   = blockIdx.x * BM;
    const int k0   = blockIdx.y * KC;
    const int tid  = threadIdx.x;
    const int wave = tid >> 6;
    const int lane = tid & 63;
    const int ll   = lane & 15;
    const int lh   = lane >> 4;
    const int lr8  = lane >> 3;                 // 0..7 row-in-group
    const int cswz = (lane & 7) ^ (lr8 & 7);    // swizzled chunk to fetch

    const ushort* Abase = A  + (size_t)(m0 + 8 * wave + lr8) * K_TOT + k0 + cswz * 8;
    const ushort* Bbase = Wt + (size_t)(32 * wave + lr8) * K_TOT      + k0 + cswz * 8;

    f32x4 acc[2][2] = {};   // [mt][nt]

#define STAGE(T, BUF)                                                        \
    do {                                                                     \
        gl_lds16(Abase + (T) * BK, &sA[BUF][8 * wave * BK]);                 \
        gl_lds16(Bbase + (T) * BK,                &sB[BUF][(32 * wave) * BK]);      \
        gl_lds16(Bbase + (T) * BK +  8 * K_TOT,   &sB[BUF][(32 * wave + 8) * BK]);  \
        gl_lds16(Bbase + (T) * BK + 16 * K_TOT,   &sB[BUF][(32 * wave + 16) * BK]); \
        gl_lds16(Bbase + (T) * BK + 24 * K_TOT,   &sB[BUF][(32 * wave + 24) * BK]); \
    } while (0)

    STAGE(0, 0);
    STAGE(1, 1);
    asm volatile("s_waitcnt vmcnt(5)" ::: "memory");
    __builtin_amdgcn_s_barrier();

    #pragma unroll
    for (int t = 0; t < NSTAGE; ++t) {
        if (t + 2 < NSTAGE) STAGE(t + 2, (t + 2) % 3);

        const int buf = t % 3;
        #pragma unroll
        for (int ks = 0; ks < 2; ++ks) {
            const int chunk = ks * 4 + lh;      // 16B chunk index
            bf16x8 bfrag[2], afrag[2];
            #pragma unroll
            for (int nt = 0; nt < 2; ++nt) {
                int br = wave * 32 + nt * 16 + ll;
                bfrag[nt] = *(const bf16x8*)&sB[buf][br * BK + ((chunk ^ (br & 7)) * 8)];
            }
            #pragma unroll
            for (int mt = 0; mt < 2; ++mt) {
                int ar = mt * 16 + ll;
                afrag[mt] = *(const bf16x8*)&sA[buf][ar * BK + ((chunk ^ (ar & 7)) * 8)];
            }
            #pragma unroll
            for (int mt = 0; mt < 2; ++mt)
                #pragma unroll
                for (int nt = 0; nt < 2; ++nt)
                    acc[mt][nt] = __builtin_amdgcn_mfma_f32_16x16x32_bf16(
                        afrag[mt], bfrag[nt], acc[mt][nt], 0, 0, 0);
        }

        if (t + 1 < NSTAGE) {
            if (t + 2 < NSTAGE)
                asm volatile("s_waitcnt vmcnt(5)" ::: "memory");
            else
                asm volatile("s_waitcnt vmcnt(0)" ::: "memory");
            __builtin_amdgcn_s_barrier();
        }
    }
#undef STAGE

    // store partial (D layout: col = lane&15, row = (lane>>4)*4 + reg)
    float* dst = part + (size_t)blockIdx.y * (N_PED * H);
    #pragma unroll
    for (int mt = 0; mt < 2; ++mt)
        #pragma unroll
        for (int nt = 0; nt < 2; ++nt) {
            int col   = wave * 32 + nt * 16 + ll;
            int rbase = m0 + mt * 16 + lh * 4;
            #pragma unroll
            for (int r = 0; r < 4; ++r)
                dst[(size_t)(rbase + r) * H + col] = acc[mt][nt][r];
        }

    // split-K semaphore
    __threadfence();
    __syncthreads();
    if (tid == 0) winner = (atomicAdd(&sem[blockIdx.x], 1) == KSPLIT - 1);
    __syncthreads();
    if (!winner) return;

    __threadfence();   // acquire: all 16 slices device-visible
    const float4* b4   = (const float4*)b;
    float4*       out4 = (float4*)out;
    const int     base = m0 * (H / 4);               // float4 index of tile start
    #pragma unroll
    for (int q = 0; q < 4; ++q) {
        int idx = q * 256 + tid;                     // 0..1023 float4 in tile
        float4 acc4 = b4[idx & 31];
        #pragma unroll
        for (int s = 0; s < KSPLIT; ++s) {
            float4 p = ((const float4*)part)[(size_t)s * (N_PED * H / 4) + base + idx];
            acc4.x += p.x; acc4.y += p.y; acc4.z += p.z; acc4.w += p.w;
        }
        out4[base + idx] = acc4;
    }
}

extern "C" void kernel_launch(void* const* d_in, const int* in_sizes, int n_in,
                              void* d_out, int out_size, void* d_ws, size_t ws_size,
                              hipStream_t stream) {
    const float* hs  = (const float*)d_in[0];   // [1024][128]
    const float* pos = (const float*)d_in[1];   // [1024][2]
    const float* Wm  = (const float*)d_in[2];   // [8192][128]
    const float* b   = (const float*)d_in[3];   // [128]
    float* out = (float*)d_out;                 // [1024][128]

    ushort* grid = (ushort*)d_ws;                               // 16 MB
    ushort* Wt   = (ushort*)((char*)d_ws + (16u << 20));        // 2 MB
    float*  part = (float*)((char*)d_ws + (18u << 20));         // 8 MB
    int*    sem  = (int*)((char*)d_ws + (26u << 20));           // 128 B

    fused_pre<<<N_PED + 128, 512, 0, stream>>>(hs, pos, Wm, grid, Wt, sem);
    gemm_mfma<<<dim3(N_PED / BM, KSPLIT), 256, 0, stream>>>(grid, Wt, part, b, out, sem);
}

// Round 10
// 33.243 us; speedup vs baseline: 7.3831x; 2.5921x over previous
//
#include <hip/hip_runtime.h>
#include <hip/hip_bf16.h>

#define N_PED 1024
#define H 128
#define G 8
#define NCELL 64
#define K_TOT 8192
#define HALF_NB 16.0f
#define INV_CELL 0.25f

#define KSPLIT 16
#define KC 512          // K per gemm block
#define BM 32
#define BK 64
#define NSTAGE 8        // KC/BK

typedef __attribute__((ext_vector_type(8))) short bf16x8;
typedef __attribute__((ext_vector_type(4))) float f32x4;

__device__ __forceinline__ unsigned map_f2u(float v) {
    unsigned u = __float_as_uint(v);
    return (u & 0x80000000u) ? ~u : (u | 0x80000000u);
}
__device__ __forceinline__ float unmap_u2f(unsigned u) {
    return __uint_as_float((u & 0x80000000u) ? (u ^ 0x80000000u) : ~u);
}
// two mapped-uints -> packed 2x bf16 (v_cvt_pk_bf16_f32, RNE)
__device__ __forceinline__ unsigned pack2(unsigned ua, unsigned ub) {
    float2 f = {unmap_u2f(ua), unmap_u2f(ub)};
    union { __hip_bfloat162 h; unsigned u; } cv;
    cv.h = __float22bfloat162_rn(f);
    return cv.u;
}
__device__ __forceinline__ unsigned pack2f(float fa, float fb) {
    float2 f = {fa, fb};
    union { __hip_bfloat162 h; unsigned u; } cv;
    cv.h = __float22bfloat162_rn(f);
    return cv.u;
}
__device__ __forceinline__ void gl_lds16(const void* g, void* l) {
    __builtin_amdgcn_global_load_lds(
        (const __attribute__((address_space(1))) void*)g,
        (__attribute__((address_space(3))) void*)l, 16, 0, 0);
}

// blocks 0..1023   : build pooled grid row (bf16 [8192]) for pedestrian i
// blocks 1024..1151: convert+transpose 64-k slab of W into Wt bf16 [128][8192]
// blocks 1152..1153: out[i][o] = b[o]  (bias seed for atomic epilogue)
__global__ __launch_bounds__(512) void fused_pre(const float* __restrict__ hs,
                                                 const float* __restrict__ pos,
                                                 const float* __restrict__ W,
                                                 const float* __restrict__ b,
                                                 ushort* __restrict__ grid,
                                                 ushort* __restrict__ Wt,
                                                 float* __restrict__ out) {
    __shared__ __align__(16) char smem[36872];
    const int tid = threadIdx.x;

    if (blockIdx.x < N_PED) {
        unsigned* lgrid = (unsigned*)smem;            // 32768 B
        int*      list  = (int*)(smem + 32768);       // 4096 B
        int*      cnt   = (int*)(smem + 36864);       // 4 B
        const int i = blockIdx.x;

        const unsigned iu = 0x80000000u;              // map_f2u(0.0f)
        uint4 iv = {iu, iu, iu, iu};
        for (int k = tid; k < NCELL * H / 4; k += 512) ((uint4*)lgrid)[k] = iv;
        if (tid == 0) *cnt = 0;
        __syncthreads();

        const float2 pi = ((const float2*)pos)[i];
        for (int j = tid; j < N_PED; j += 512) {
            float2 pj = ((const float2*)pos)[j];
            float rx = pj.x - pi.x;
            float ry = pj.y - pi.y;
            if (j != i && fabsf(rx) <= HALF_NB && fabsf(ry) <= HALF_NB) {
                int gx = min(G - 1, max(0, (int)floorf((rx + HALF_NB) * INV_CELL)));
                int gy = min(G - 1, max(0, (int)floorf((ry + HALF_NB) * INV_CELL)));
                int slot = atomicAdd(cnt, 1);
                list[slot] = (j << 8) | (gy * G + gx);
            }
        }
        __syncthreads();

        // pooling: 16-way entry parallel; lane c owns dims {c,c+32,c+64,c+96}
        // -> atomic bank = c: conflict-free across the 32-lane group (m136)
        const int n  = *cnt;
        const int c  = tid & 31;
        const int eg = tid >> 5;                      // 0..15
        int e  = eg;
        int p0 = (e < n) ? list[e] : -1;
        int p1 = (e + 16 < n) ? list[e + 16] : -1;
        float v0[4] = {};
        if (p0 >= 0) {
            const float* hp = &hs[(p0 >> 8) * H + c];
            v0[0] = hp[0]; v0[1] = hp[32]; v0[2] = hp[64]; v0[3] = hp[96];
        }
        while (p0 >= 0) {
            int p2 = (e + 32 < n) ? list[e + 32] : -1;
            float v1[4] = {};
            if (p1 >= 0) {
                const float* hp = &hs[(p1 >> 8) * H + c];
                v1[0] = hp[0]; v1[1] = hp[32]; v1[2] = hp[64]; v1[3] = hp[96];
            }
            unsigned* gph = &lgrid[(p0 & 255) * H + c];
            atomicMax(gph + 0,  map_f2u(v0[0]));
            atomicMax(gph + 32, map_f2u(v0[1]));
            atomicMax(gph + 64, map_f2u(v0[2]));
            atomicMax(gph + 96, map_f2u(v0[3]));
            e += 16; p0 = p1; p1 = p2;
            v0[0] = v1[0]; v0[1] = v1[1]; v0[2] = v1[2]; v0[3] = v1[3];
        }
        __syncthreads();

        // writeout: unmap + v_cvt_pk_bf16_f32 pairs (half the VALU of scalar f2bf)
        uint4* dst = (uint4*)(grid + (size_t)i * K_TOT);
        for (int q = tid; q < K_TOT / 8; q += 512) {
            uint4 a  = ((const uint4*)lgrid)[2 * q];
            uint4 bq = ((const uint4*)lgrid)[2 * q + 1];
            uint4 o;
            o.x = pack2(a.x,  a.y);
            o.y = pack2(a.z,  a.w);
            o.z = pack2(bq.x, bq.y);
            o.w = pack2(bq.z, bq.w);
            dst[q] = o;
        }
    } else if (blockIdx.x < N_PED + 128) {
        float* tile = (float*)smem;                   // [64][129] = 33024 B
        const int bw  = blockIdx.x - N_PED;
        const int k0w = bw * 64;

        for (int x = tid; x < 64 * H; x += 512) {
            int r = x >> 7, cc = x & 127;
            tile[r * 129 + cc] = W[(size_t)(k0w + r) * H + cc];
        }
        __syncthreads();

        const int col = tid >> 2;                     // 0..127
        const int kh  = (tid & 3) * 16;
        uint tmp[8];
        #pragma unroll
        for (int t = 0; t < 8; ++t)
            tmp[t] = pack2f(tile[(kh + 2 * t) * 129 + col],
                            tile[(kh + 2 * t + 1) * 129 + col]);
        uint4* w0 = (uint4*)(Wt + (size_t)col * K_TOT + k0w + kh);
        w0[0] = *(const uint4*)&tmp[0];
        w0[1] = *(const uint4*)&tmp[4];
    } else {
        const float4* b4 = (const float4*)b;
        float4* out4 = (float4*)out;
        const int b0 = (blockIdx.x - N_PED - 128) * 16384;
        for (int i2 = tid; i2 < 16384; i2 += 512) {
            int g = b0 + i2;
            out4[g] = b4[g & 31];
        }
    }
}

// A[1024][8192] bf16 @ Wt[128][8192] bf16, split-K 16x; fire-and-forget fp32
// atomicAdd epilogue into bias-seeded out (no fences, no part, no 3rd launch).
__global__ __launch_bounds__(256) void gemm_mfma(const ushort* __restrict__ A,
                                                 const ushort* __restrict__ Wt,
                                                 float* __restrict__ out) {
    __shared__ ushort sA[3][BM * BK];   // 3 x 4 KB
    __shared__ ushort sB[3][H * BK];    // 3 x 16 KB

    const int m0   = blockIdx.x * BM;
    const int k0   = blockIdx.y * KC;
    const int tid  = threadIdx.x;
    const int wave = tid >> 6;
    const int lane = tid & 63;
    const int ll   = lane & 15;
    const int lh   = lane >> 4;
    const int lr8  = lane >> 3;                 // 0..7 row-in-group
    const int cswz = (lane & 7) ^ (lr8 & 7);    // swizzled chunk to fetch

    const ushort* Abase = A  + (size_t)(m0 + 8 * wave + lr8) * K_TOT + k0 + cswz * 8;
    const ushort* Bbase = Wt + (size_t)(32 * wave + lr8) * K_TOT      + k0 + cswz * 8;

    f32x4 acc[2][2] = {};   // [mt][nt]

#define STAGE(T, BUF)                                                        \
    do {                                                                     \
        gl_lds16(Abase + (T) * BK, &sA[BUF][8 * wave * BK]);                 \
        gl_lds16(Bbase + (T) * BK,                &sB[BUF][(32 * wave) * BK]);      \
        gl_lds16(Bbase + (T) * BK +  8 * K_TOT,   &sB[BUF][(32 * wave + 8) * BK]);  \
        gl_lds16(Bbase + (T) * BK + 16 * K_TOT,   &sB[BUF][(32 * wave + 16) * BK]); \
        gl_lds16(Bbase + (T) * BK + 24 * K_TOT,   &sB[BUF][(32 * wave + 24) * BK]); \
    } while (0)

    STAGE(0, 0);
    STAGE(1, 1);
    asm volatile("s_waitcnt vmcnt(5)" ::: "memory");
    __builtin_amdgcn_s_barrier();

    #pragma unroll
    for (int t = 0; t < NSTAGE; ++t) {
        if (t + 2 < NSTAGE) STAGE(t + 2, (t + 2) % 3);

        const int buf = t % 3;
        #pragma unroll
        for (int ks = 0; ks < 2; ++ks) {
            const int chunk = ks * 4 + lh;      // 16B chunk index
            bf16x8 bfrag[2], afrag[2];
            #pragma unroll
            for (int nt = 0; nt < 2; ++nt) {
                int br = wave * 32 + nt * 16 + ll;
                bfrag[nt] = *(const bf16x8*)&sB[buf][br * BK + ((chunk ^ (br & 7)) * 8)];
            }
            #pragma unroll
            for (int mt = 0; mt < 2; ++mt) {
                int ar = mt * 16 + ll;
                afrag[mt] = *(const bf16x8*)&sA[buf][ar * BK + ((chunk ^ (ar & 7)) * 8)];
            }
            #pragma unroll
            for (int mt = 0; mt < 2; ++mt)
                #pragma unroll
                for (int nt = 0; nt < 2; ++nt)
                    acc[mt][nt] = __builtin_amdgcn_mfma_f32_16x16x32_bf16(
                        afrag[mt], bfrag[nt], acc[mt][nt], 0, 0, 0);
        }

        if (t + 1 < NSTAGE) {
            if (t + 2 < NSTAGE)
                asm volatile("s_waitcnt vmcnt(5)" ::: "memory");
            else
                asm volatile("s_waitcnt vmcnt(0)" ::: "memory");
            __builtin_amdgcn_s_barrier();
        }
    }
#undef STAGE

    // epilogue: fire-and-forget atomics (no return value -> no wait),
    // D layout: col = lane&15, row = (lane>>4)*4 + reg   [m89/m91]
    #pragma unroll
    for (int mt = 0; mt < 2; ++mt)
        #pragma unroll
        for (int nt = 0; nt < 2; ++nt) {
            int col   = wave * 32 + nt * 16 + ll;
            int rbase = m0 + mt * 16 + lh * 4;
            #pragma unroll
            for (int r = 0; r < 4; ++r)
                atomicAdd(&out[(size_t)(rbase + r) * H + col], acc[mt][nt][r]);
        }
}

extern "C" void kernel_launch(void* const* d_in, const int* in_sizes, int n_in,
                              void* d_out, int out_size, void* d_ws, size_t ws_size,
                              hipStream_t stream) {
    const float* hs  = (const float*)d_in[0];   // [1024][128]
    const float* pos = (const float*)d_in[1];   // [1024][2]
    const float* Wm  = (const float*)d_in[2];   // [8192][128]
    const float* b   = (const float*)d_in[3];   // [128]
    float* out = (float*)d_out;                 // [1024][128]

    ushort* grid = (ushort*)d_ws;                               // 16 MB
    ushort* Wt   = (ushort*)((char*)d_ws + (16u << 20));        // 2 MB

    fused_pre<<<N_PED + 128 + 2, 512, 0, stream>>>(hs, pos, Wm, b, grid, Wt, out);
    gemm_mfma<<<dim3(N_PED / BM, KSPLIT), 256, 0, stream>>>(grid, Wt, out);
}

// Round 13
// 28.765 us; speedup vs baseline: 8.5323x; 1.1557x over previous
//
#include <hip/hip_runtime.h>
#include <hip/hip_bf16.h>

#define N_PED 1024
#define H 128
#define G 8
#define NCELL 64
#define K_TOT 8192
#define HALF_NB 16.0f
#define INV_CELL 0.25f

#define KSPLIT 16
#define KC 512          // K per gemm block
#define BM 64
#define BK 64
#define NSTAGE 8        // KC/BK

typedef __attribute__((ext_vector_type(8))) short bf16x8;
typedef __attribute__((ext_vector_type(4))) float f32x4;

__device__ __forceinline__ unsigned map_f2u(float v) {
    unsigned u = __float_as_uint(v);
    return (u & 0x80000000u) ? ~u : (u | 0x80000000u);
}
__device__ __forceinline__ float unmap_u2f(unsigned u) {
    return __uint_as_float((u & 0x80000000u) ? (u ^ 0x80000000u) : ~u);
}
// pack two fp32 -> 2x bf16 (v_cvt_pk_bf16_f32, RNE)
__device__ __forceinline__ unsigned pack2(unsigned ua, unsigned ub) {
    float2 f = {unmap_u2f(ua), unmap_u2f(ub)};
    union { __hip_bfloat162 h; unsigned u; } cv;
    cv.h = __float22bfloat162_rn(f);
    return cv.u;
}
__device__ __forceinline__ unsigned pack2f(float fa, float fb) {
    float2 f = {fa, fb};
    union { __hip_bfloat162 h; unsigned u; } cv;
    cv.h = __float22bfloat162_rn(f);
    return cv.u;
}
__device__ __forceinline__ void gl_lds16(const void* g, void* l) {
    __builtin_amdgcn_global_load_lds(
        (const __attribute__((address_space(1))) void*)g,
        (__attribute__((address_space(3))) void*)l, 16, 0, 0);
}

// blocks 0..1023   : build pooled grid row (bf16 [8192]) for pedestrian i
// blocks 1024..1151: convert+transpose 64-k slab of W into Wt bf16 [128][8192]
__global__ __launch_bounds__(512) void fused_pre(const float* __restrict__ hs,
                                                 const float* __restrict__ pos,
                                                 const float* __restrict__ W,
                                                 ushort* __restrict__ grid,
                                                 ushort* __restrict__ Wt) {
    __shared__ __align__(16) char smem[36872];
    const int tid = threadIdx.x;

    if (blockIdx.x < N_PED) {
        unsigned* lgrid = (unsigned*)smem;            // 32768 B
        int*      list  = (int*)(smem + 32768);       // 4096 B
        int*      cnt   = (int*)(smem + 36864);       // 4 B
        const int i = blockIdx.x;

        const unsigned iu = 0x80000000u;              // map_f2u(0.0f)
        uint4 iv = {iu, iu, iu, iu};
        for (int k = tid; k < NCELL * H / 4; k += 512) ((uint4*)lgrid)[k] = iv;
        if (tid == 0) *cnt = 0;
        __syncthreads();

        const float2 pi = ((const float2*)pos)[i];
        for (int j = tid; j < N_PED; j += 512) {
            float2 pj = ((const float2*)pos)[j];
            float rx = pj.x - pi.x;
            float ry = pj.y - pi.y;
            if (j != i && fabsf(rx) <= HALF_NB && fabsf(ry) <= HALF_NB) {
                int gx = min(G - 1, max(0, (int)floorf((rx + HALF_NB) * INV_CELL)));
                int gy = min(G - 1, max(0, (int)floorf((ry + HALF_NB) * INV_CELL)));
                int slot = atomicAdd(cnt, 1);
                list[slot] = (j << 8) | (gy * G + gx);
            }
        }
        __syncthreads();

        // pooling: 16-way entry parallel; lane c owns dims {c,c+32,c+64,c+96}
        // -> atomic bank = c: conflict-free across the 32-lane group (m136)
        const int n  = *cnt;
        const int c  = tid & 31;
        const int eg = tid >> 5;                      // 0..15
        int e  = eg;
        int p0 = (e < n) ? list[e] : -1;
        int p1 = (e + 16 < n) ? list[e + 16] : -1;
        float v0[4] = {};
        if (p0 >= 0) {
            const float* hp = &hs[(p0 >> 8) * H + c];
            v0[0] = hp[0]; v0[1] = hp[32]; v0[2] = hp[64]; v0[3] = hp[96];
        }
        while (p0 >= 0) {
            int p2 = (e + 32 < n) ? list[e + 32] : -1;
            float v1[4] = {};
            if (p1 >= 0) {
                const float* hp = &hs[(p1 >> 8) * H + c];
                v1[0] = hp[0]; v1[1] = hp[32]; v1[2] = hp[64]; v1[3] = hp[96];
            }
            unsigned* gph = &lgrid[(p0 & 255) * H + c];
            atomicMax(gph + 0,  map_f2u(v0[0]));
            atomicMax(gph + 32, map_f2u(v0[1]));
            atomicMax(gph + 64, map_f2u(v0[2]));
            atomicMax(gph + 96, map_f2u(v0[3]));
            e += 16; p0 = p1; p1 = p2;
            v0[0] = v1[0]; v0[1] = v1[1]; v0[2] = v1[2]; v0[3] = v1[3];
        }
        __syncthreads();

        // writeout: unmap + v_cvt_pk_bf16_f32 pairs
        uint4* dst = (uint4*)(grid + (size_t)i * K_TOT);
        for (int q = tid; q < K_TOT / 8; q += 512) {
            uint4 a  = ((const uint4*)lgrid)[2 * q];
            uint4 bq = ((const uint4*)lgrid)[2 * q + 1];
            uint4 o;
            o.x = pack2(a.x,  a.y);
            o.y = pack2(a.z,  a.w);
            o.z = pack2(bq.x, bq.y);
            o.w = pack2(bq.z, bq.w);
            dst[q] = o;
        }
    } else {
        float* tile = (float*)smem;                   // [64][129] = 33024 B
        const int bw  = blockIdx.x - N_PED;
        const int k0w = bw * 64;

        for (int x = tid; x < 64 * H; x += 512) {
            int r = x >> 7, cc = x & 127;
            tile[r * 129 + cc] = W[(size_t)(k0w + r) * H + cc];
        }
        __syncthreads();

        const int col = tid >> 2;                     // 0..127
        const int kh  = (tid & 3) * 16;
        uint tmp[8];
        #pragma unroll
        for (int t = 0; t < 8; ++t)
            tmp[t] = pack2f(tile[(kh + 2 * t) * 129 + col],
                            tile[(kh + 2 * t + 1) * 129 + col]);
        uint4* w0 = (uint4*)(Wt + (size_t)col * K_TOT + k0w + kh);
        w0[0] = *(const uint4*)&tmp[0];
        w0[1] = *(const uint4*)&tmp[4];
    }
}

// A[1024][8192] bf16 @ Wt[128][8192] bf16 -> part [KSPLIT][1024][128] fp32.
// BM=64, 512 thr (8 waves, 2m x 4n, wave tile 32x32): halves L2 B-traffic vs
// BM=32 and gives x2 intra-block B reuse. Triple-buffered LDS, counted
// vmcnt(3), chunk-XOR swizzle both sides (rule #21). LDS 72KB -> 2 blocks/CU.
__global__ __launch_bounds__(512) void gemm_mfma(const ushort* __restrict__ A,
                                                 const ushort* __restrict__ Wt,
                                                 float* __restrict__ part) {
    __shared__ ushort sA[3][BM * BK];   // 3 x 8 KB
    __shared__ ushort sB[3][H * BK];    // 3 x 16 KB

    const int m0   = blockIdx.x * BM;
    const int k0   = blockIdx.y * KC;
    const int tid  = threadIdx.x;
    const int wave = tid >> 6;
    const int lane = tid & 63;
    const int ll   = lane & 15;
    const int lh   = lane >> 4;
    const int lr8  = lane >> 3;                 // 0..7 row-in-group
    const int cswz = (lane & 7) ^ (lr8 & 7);    // swizzled chunk to fetch
    const int wr   = wave >> 2;                 // 0..1  (m half)
    const int wc   = wave & 3;                  // 0..3  (n quarter)

    // staging bases: wave stages A rows 8w..8w+7 and Wt rows (out cols) 16w..16w+15
    const ushort* Abase = A  + (size_t)(m0 + 8 * wave + lr8) * K_TOT + k0 + cswz * 8;
    const ushort* Bbase = Wt + (size_t)(16 * wave + lr8) * K_TOT     + k0 + cswz * 8;

    f32x4 acc[2][2] = {};   // [mt][nt]

#define STAGE(T, BUF)                                                          \
    do {                                                                       \
        gl_lds16(Abase + (T) * BK, &sA[BUF][(8 * wave) * BK]);                 \
        gl_lds16(Bbase + (T) * BK,              &sB[BUF][(16 * wave) * BK]);   \
        gl_lds16(Bbase + (T) * BK + 8 * K_TOT,  &sB[BUF][(16 * wave + 8) * BK]); \
    } while (0)

    STAGE(0, 0);
    STAGE(1, 1);
    asm volatile("s_waitcnt vmcnt(3)" ::: "memory");
    __builtin_amdgcn_s_barrier();

    #pragma unroll
    for (int t = 0; t < NSTAGE; ++t) {
        if (t + 2 < NSTAGE) STAGE(t + 2, (t + 2) % 3);

        const int buf = t % 3;
        #pragma unroll
        for (int ks = 0; ks < 2; ++ks) {
            const int ch = ks * 4 + lh;         // 16B chunk index in BK
            bf16x8 afrag[2], bfrag[2];
            #pragma unroll
            for (int mt = 0; mt < 2; ++mt) {
                int ar = wr * 32 + mt * 16 + ll;
                afrag[mt] = *(const bf16x8*)&sA[buf][ar * BK + ((ch ^ (ar & 7)) * 8)];
            }
            #pragma unroll
            for (int nt = 0; nt < 2; ++nt) {
                int br = wc * 32 + nt * 16 + ll;
                bfrag[nt] = *(const bf16x8*)&sB[buf][br * BK + ((ch ^ (br & 7)) * 8)];
            }
            #pragma unroll
            for (int mt = 0; mt < 2; ++mt)
                #pragma unroll
                for (int nt = 0; nt < 2; ++nt)
                    acc[mt][nt] = __builtin_amdgcn_mfma_f32_16x16x32_bf16(
                        afrag[mt], bfrag[nt], acc[mt][nt], 0, 0, 0);
        }

        if (t + 1 < NSTAGE) {
            if (t + 2 < NSTAGE)
                asm volatile("s_waitcnt vmcnt(3)" ::: "memory");
            else
                asm volatile("s_waitcnt vmcnt(0)" ::: "memory");
            __builtin_amdgcn_s_barrier();
        }
    }
#undef STAGE

    // store partial (D layout: col = lane&15, row = (lane>>4)*4 + reg)
    float* dst = part + (size_t)blockIdx.y * (N_PED * H);
    #pragma unroll
    for (int mt = 0; mt < 2; ++mt)
        #pragma unroll
        for (int nt = 0; nt < 2; ++nt) {
            int col   = wc * 32 + nt * 16 + ll;
            int rbase = m0 + wr * 32 + mt * 16 + lh * 4;
            #pragma unroll
            for (int r = 0; r < 4; ++r)
                dst[(size_t)(rbase + r) * H + col] = acc[mt][nt][r];
        }
}

// out = bias + sum over KSPLIT partials
__global__ __launch_bounds__(128) void reduce_out(const float* __restrict__ part,
                                                  const float* __restrict__ b,
                                                  float* __restrict__ out) {
    const int idx = (blockIdx.x * 128 + threadIdx.x) * 4;   // 256 blocks
    float4 acc = *(const float4*)&b[idx & (H - 1)];
    #pragma unroll
    for (int s = 0; s < KSPLIT; ++s) {
        float4 p = *(const float4*)&part[(size_t)s * (N_PED * H) + idx];
        acc.x += p.x; acc.y += p.y; acc.z += p.z; acc.w += p.w;
    }
    *(float4*)&out[idx] = acc;
}

extern "C" void kernel_launch(void* const* d_in, const int* in_sizes, int n_in,
                              void* d_out, int out_size, void* d_ws, size_t ws_size,
                              hipStream_t stream) {
    const float* hs  = (const float*)d_in[0];   // [1024][128]
    const float* pos = (const float*)d_in[1];   // [1024][2]
    const float* Wm  = (const float*)d_in[2];   // [8192][128]
    const float* b   = (const float*)d_in[3];   // [128]
    float* out = (float*)d_out;                 // [1024][128]

    ushort* grid = (ushort*)d_ws;                               // 16 MB
    ushort* Wt   = (ushort*)((char*)d_ws + (16u << 20));        // 2 MB
    float*  part = (float*)((char*)d_ws + (18u << 20));         // 8 MB

    fused_pre<<<N_PED + 128, 512, 0, stream>>>(hs, pos, Wm, grid, Wt);
    gemm_mfma<<<dim3(N_PED / BM, KSPLIT), 512, 0, stream>>>(grid, Wt, part);
    reduce_out<<<(N_PED * H) / (128 * 4), 128, 0, stream>>>(part, b, out);
}